// Round 5
// baseline (648.381 us; speedup 1.0000x reference)
//
#include <hip/hip_runtime.h>
#include <stdint.h>

// ---------- helpers ----------
typedef __attribute__((ext_vector_type(8))) short short8;   // 8 x bf16 (4 VGPRs)
typedef __attribute__((ext_vector_type(4))) float floatx4;  // MFMA accum

__device__ __forceinline__ unsigned short f2bf(float f) {
  union { float f; unsigned int u; } c; c.f = f;
  unsigned int u = c.u;
  unsigned int r = (u + 0x7fffu + ((u >> 16) & 1u)) >> 16;  // RNE
  return (unsigned short)r;
}
__device__ __forceinline__ float bf2f(unsigned short h) {
  union { unsigned int u; float f; } c; c.u = ((unsigned int)h) << 16;
  return c.f;
}

// async global->LDS, 16B per lane. LDS dest is wave-uniform base + lane*16.
__device__ __forceinline__ void load16_to_lds(const void* g, void* l) {
  __builtin_amdgcn_global_load_lds(
      (const __attribute__((address_space(1))) unsigned int*)g,
      (__attribute__((address_space(3))) unsigned int*)l, 16, 0, 0);
}

// ---------- elementwise kernels ----------
__global__ void f32_to_bf16_kernel(const float* __restrict__ in,
                                   unsigned short* __restrict__ out, long n4) {
  long i = blockIdx.x * (long)blockDim.x + threadIdx.x;
  if (i >= n4) return;
  float4 v = ((const float4*)in)[i];
  ushort4 o;
  o.x = f2bf(v.x); o.y = f2bf(v.y); o.z = f2bf(v.z); o.w = f2bf(v.w);
  ((ushort4*)out)[i] = o;
}

// Dequant w1 AND w3 in one pass (same shape/scale layout). 2D grid kills the
// int64 div: n = blockIdx.y, k = blockIdx.x*1024 + tid*4.
__global__ void dequant2_kernel(const float* __restrict__ w1q,
                                const float* __restrict__ s1,
                                const float* __restrict__ w3q,
                                const float* __restrict__ s3,
                                unsigned short* __restrict__ o1,
                                unsigned short* __restrict__ o3,
                                int K, int sK) {
  int n = blockIdx.y;
  int k = blockIdx.x * 1024 + threadIdx.x * 4;
  size_t idx = (size_t)n * K + k;
  int sidx = (n >> 7) * sK + (k >> 7);
  float sc1 = s1[sidx], sc3 = s3[sidx];
  float4 v1 = *(const float4*)(w1q + idx);
  float4 v3 = *(const float4*)(w3q + idx);
  ushort4 a, b;
  a.x = f2bf(v1.x * sc1); a.y = f2bf(v1.y * sc1);
  a.z = f2bf(v1.z * sc1); a.w = f2bf(v1.w * sc1);
  b.x = f2bf(v3.x * sc3); b.y = f2bf(v3.y * sc3);
  b.z = f2bf(v3.z * sc3); b.w = f2bf(v3.w * sc3);
  *(ushort4*)(o1 + idx) = a;
  *(ushort4*)(o3 + idx) = b;
}

__global__ void dequant1_kernel(const float* __restrict__ wq,
                                const float* __restrict__ s,
                                unsigned short* __restrict__ out,
                                int K, int sK) {
  int n = blockIdx.y;
  int k = blockIdx.x * 1024 + threadIdx.x * 4;
  size_t idx = (size_t)n * K + k;
  float sc = s[(n >> 7) * sK + (k >> 7)];
  float4 v = *(const float4*)(wq + idx);
  ushort4 o;
  o.x = f2bf(v.x * sc); o.y = f2bf(v.y * sc);
  o.z = f2bf(v.z * sc); o.w = f2bf(v.w * sc);
  *(ushort4*)(out + idx) = o;
}

// ---------- merged dual GEMM + silu: C = silu(A*B1^T) .* (A*B3^T) ----------
// 512 threads = 8 waves; wave-tile 64(M)x32(N) for BOTH g and u. 844 TF
// measured (R4) — at the m97-structure plateau.
__global__ __launch_bounds__(512, 4) void dual_gemm_silu(
    const unsigned short* __restrict__ A,   // [M,K] bf16 (x)
    const unsigned short* __restrict__ B1,  // [N,K] bf16 (w1)
    const unsigned short* __restrict__ B3,  // [N,K] bf16 (w3)
    unsigned short* __restrict__ C,         // [M,N] bf16 fused
    int M, int N, int K) {
  __shared__ unsigned short As[128 * 32];
  __shared__ unsigned short B1s[128 * 32];
  __shared__ unsigned short B3s[128 * 32];

  const int tid = threadIdx.x;
  const int lane = tid & 63;
  const int wave = tid >> 6;      // 0..7
  const int wm = wave >> 2;       // 0..1  (M 64-half)
  const int wn = wave & 3;        // 0..3  (N 32-quarter)
  const int m0 = blockIdx.y * 128, n0 = blockIdx.x * 128;

  const int f0 = tid * 8;
  const int ar = tid >> 2;        // 0..127
  const int ac = (tid & 3) * 8;

  const int q = lane >> 4;        // quad -> k offset q*8, out-row base q*4
  const int r16 = lane & 15;

  floatx4 acc_g[4][2], acc_u[4][2];
#pragma unroll
  for (int i = 0; i < 4; i++)
#pragma unroll
    for (int j = 0; j < 2; j++) {
      acc_g[i][j] = (floatx4){0.f, 0.f, 0.f, 0.f};
      acc_u[i][j] = (floatx4){0.f, 0.f, 0.f, 0.f};
    }

  const unsigned short* ag = A + (size_t)(m0 + ar) * K + ac;
  const unsigned short* b1g = B1 + (size_t)(n0 + ar) * K + ac;
  const unsigned short* b3g = B3 + (size_t)(n0 + ar) * K + ac;

  for (int k0 = 0; k0 < K; k0 += 32) {
    load16_to_lds(ag + k0, &As[f0]);
    load16_to_lds(b1g + k0, &B1s[f0]);
    load16_to_lds(b3g + k0, &B3s[f0]);
    __syncthreads();

    short8 a[4], b1[2], b3[2];
#pragma unroll
    for (int t = 0; t < 4; t++)
      a[t] = *(const short8*)&As[(wm * 64 + t * 16 + r16) * 32 + q * 8];
#pragma unroll
    for (int j = 0; j < 2; j++) {
      b1[j] = *(const short8*)&B1s[(wn * 32 + j * 16 + r16) * 32 + q * 8];
      b3[j] = *(const short8*)&B3s[(wn * 32 + j * 16 + r16) * 32 + q * 8];
    }
#pragma unroll
    for (int i = 0; i < 4; i++)
#pragma unroll
      for (int j = 0; j < 2; j++) {
        acc_g[i][j] =
            __builtin_amdgcn_mfma_f32_16x16x32_bf16(a[i], b1[j], acc_g[i][j], 0, 0, 0);
        acc_u[i][j] =
            __builtin_amdgcn_mfma_f32_16x16x32_bf16(a[i], b3[j], acc_u[i][j], 0, 0, 0);
      }
    __syncthreads();
  }

  // epilogue: D col = lane&15, row = quad*4 + reg (m89/m91-verified)
#pragma unroll
  for (int i = 0; i < 4; i++) {
    int row0 = m0 + wm * 64 + i * 16 + q * 4;
#pragma unroll
    for (int j = 0; j < 2; j++) {
      int col = n0 + wn * 32 + j * 16 + r16;
#pragma unroll
      for (int rr = 0; rr < 4; rr++) {
        float gv = acc_g[i][j][rr];
        float uv = acc_u[i][j][rr];
        float sv = gv / (1.f + __expf(-gv)) * uv;
        C[(size_t)(row0 + rr) * N + col] = f2bf(sv);
      }
    }
  }
}

// ---------- GEMM3: C[M,N] = A[M,K] * B[N,K]^T, bf16 in, fp32 out ----------
// 8-wave port of the dual structure (single B). Rationale: the 256-thread
// version at grid=512 blocks gives only 2 blocks/CU x 4 waves = 8 waves/CU
// (25% occupancy) -> 587 TF. 512-thread blocks keep grid=512 but double
// resident waves to 16/CU, matching the dual kernel's 844 TF regime.
__global__ __launch_bounds__(512, 4) void gemm_nt_f32_8w(
    const unsigned short* __restrict__ A,  // [M,K] bf16
    const unsigned short* __restrict__ B,  // [N,K] bf16
    float* __restrict__ C,                 // [M,N] fp32
    int M, int N, int K) {
  __shared__ unsigned short As[128 * 32];
  __shared__ unsigned short Bs[128 * 32];

  const int tid = threadIdx.x;
  const int lane = tid & 63;
  const int wave = tid >> 6;
  const int wm = wave >> 2;       // 0..1
  const int wn = wave & 3;        // 0..3
  const int m0 = blockIdx.y * 128, n0 = blockIdx.x * 128;

  const int f0 = tid * 8;
  const int ar = tid >> 2;        // 0..127
  const int ac = (tid & 3) * 8;

  const int q = lane >> 4;
  const int r16 = lane & 15;

  floatx4 acc[4][2];
#pragma unroll
  for (int i = 0; i < 4; i++)
#pragma unroll
    for (int j = 0; j < 2; j++) acc[i][j] = (floatx4){0.f, 0.f, 0.f, 0.f};

  const unsigned short* ag = A + (size_t)(m0 + ar) * K + ac;
  const unsigned short* bg = B + (size_t)(n0 + ar) * K + ac;

  for (int k0 = 0; k0 < K; k0 += 32) {
    load16_to_lds(ag + k0, &As[f0]);
    load16_to_lds(bg + k0, &Bs[f0]);
    __syncthreads();

    short8 a[4], b[2];
#pragma unroll
    for (int t = 0; t < 4; t++)
      a[t] = *(const short8*)&As[(wm * 64 + t * 16 + r16) * 32 + q * 8];
#pragma unroll
    for (int j = 0; j < 2; j++)
      b[j] = *(const short8*)&Bs[(wn * 32 + j * 16 + r16) * 32 + q * 8];
#pragma unroll
    for (int i = 0; i < 4; i++)
#pragma unroll
      for (int j = 0; j < 2; j++)
        acc[i][j] =
            __builtin_amdgcn_mfma_f32_16x16x32_bf16(a[i], b[j], acc[i][j], 0, 0, 0);
    __syncthreads();
  }

#pragma unroll
  for (int i = 0; i < 4; i++) {
    int row0 = m0 + wm * 64 + i * 16 + q * 4;
#pragma unroll
    for (int j = 0; j < 2; j++) {
      int col = n0 + wn * 32 + j * 16 + r16;
#pragma unroll
      for (int rr = 0; rr < 4; rr++)
        C[(size_t)(row0 + rr) * N + col] = acc[i][j][rr];
    }
  }
}

// ---------- launch ----------
extern "C" void kernel_launch(void* const* d_in, const int* in_sizes, int n_in,
                              void* d_out, int out_size, void* d_ws, size_t ws_size,
                              hipStream_t stream) {
  const float* x = (const float*)d_in[0];
  const float* w1q = (const float*)d_in[1];
  const float* w1s = (const float*)d_in[2];
  const float* w3q = (const float*)d_in[3];
  const float* w3s = (const float*)d_in[4];
  const float* w2q = (const float*)d_in[5];
  const float* w2s = (const float*)d_in[6];

  const int T = 4096, H = 2048, F = 7168;

  char* ws = (char*)d_ws;
  unsigned short* xb  = (unsigned short*)ws;  ws += (size_t)T * H * 2;   // 16.8 MB
  unsigned short* w1b = (unsigned short*)ws;  ws += (size_t)F * H * 2;   // 29.4 MB
  unsigned short* w3b = (unsigned short*)ws;  ws += (size_t)F * H * 2;   // 29.4 MB
  unsigned short* w2b = (unsigned short*)ws;  ws += (size_t)H * F * 2;   // 29.4 MB
  unsigned short* g   = (unsigned short*)ws;  ws += (size_t)T * F * 2;   // 58.7 MB
  // total ~164 MB of d_ws

  long xn4 = (long)T * H / 4;

  f32_to_bf16_kernel<<<(xn4 + 255) / 256, 256, 0, stream>>>(x, xb, xn4);
  // w1+w3 dequant in one pass: K=H=2048 -> grid (2, F)
  dequant2_kernel<<<dim3(H / 1024, F), 256, 0, stream>>>(
      w1q, w1s, w3q, w3s, w1b, w3b, H, H / 128);
  // w2 dequant: K=F=7168 -> grid (7, H)
  dequant1_kernel<<<dim3(F / 1024, H), 256, 0, stream>>>(
      w2q, w2s, w2b, F, F / 128);

  // g = silu(x @ w1^T) * (x @ w3^T)  — single fused pass
  dual_gemm_silu<<<dim3(F / 128, T / 128), 512, 0, stream>>>(xb, w1b, w3b, g, T, F, H);

  // out = g @ w2^T  (fp32 out)
  gemm_nt_f32_8w<<<dim3(H / 128, T / 128), 512, 0, stream>>>(g, w2b, (float*)d_out, T, H, F);
}

// Round 6
// 573.745 us; speedup vs baseline: 1.1301x; 1.1301x over previous
//
#include <hip/hip_runtime.h>
#include <stdint.h>

// ---------- helpers ----------
typedef __attribute__((ext_vector_type(8))) short short8;   // 8 x bf16 (4 VGPRs)
typedef __attribute__((ext_vector_type(4))) float floatx4;  // MFMA accum

__device__ __forceinline__ unsigned short f2bf(float f) {
  union { float f; unsigned int u; } c; c.f = f;
  unsigned int u = c.u;
  unsigned int r = (u + 0x7fffu + ((u >> 16) & 1u)) >> 16;  // RNE
  return (unsigned short)r;
}
__device__ __forceinline__ float bf2f(unsigned short h) {
  union { unsigned int u; float f; } c; c.u = ((unsigned int)h) << 16;
  return c.f;
}

// async global->LDS, 16B per lane. LDS dest is wave-uniform base + lane*16.
__device__ __forceinline__ void load16_to_lds(const void* g, void* l) {
  __builtin_amdgcn_global_load_lds(
      (const __attribute__((address_space(1))) unsigned int*)g,
      (__attribute__((address_space(3))) unsigned int*)l, 16, 0, 0);
}

// ---------- elementwise kernels ----------
__global__ void f32_to_bf16_kernel(const float* __restrict__ in,
                                   unsigned short* __restrict__ out, long n4) {
  long i = blockIdx.x * (long)blockDim.x + threadIdx.x;
  if (i >= n4) return;
  float4 v = ((const float4*)in)[i];
  ushort4 o;
  o.x = f2bf(v.x); o.y = f2bf(v.y); o.z = f2bf(v.z); o.w = f2bf(v.w);
  ((ushort4*)out)[i] = o;
}

__global__ void dequant2_kernel(const float* __restrict__ w1q,
                                const float* __restrict__ s1,
                                const float* __restrict__ w3q,
                                const float* __restrict__ s3,
                                unsigned short* __restrict__ o1,
                                unsigned short* __restrict__ o3,
                                int K, int sK) {
  int n = blockIdx.y;
  int k = blockIdx.x * 1024 + threadIdx.x * 4;
  size_t idx = (size_t)n * K + k;
  int sidx = (n >> 7) * sK + (k >> 7);
  float sc1 = s1[sidx], sc3 = s3[sidx];
  float4 v1 = *(const float4*)(w1q + idx);
  float4 v3 = *(const float4*)(w3q + idx);
  ushort4 a, b;
  a.x = f2bf(v1.x * sc1); a.y = f2bf(v1.y * sc1);
  a.z = f2bf(v1.z * sc1); a.w = f2bf(v1.w * sc1);
  b.x = f2bf(v3.x * sc3); b.y = f2bf(v3.y * sc3);
  b.z = f2bf(v3.z * sc3); b.w = f2bf(v3.w * sc3);
  *(ushort4*)(o1 + idx) = a;
  *(ushort4*)(o3 + idx) = b;
}

__global__ void dequant1_kernel(const float* __restrict__ wq,
                                const float* __restrict__ s,
                                unsigned short* __restrict__ out,
                                int K, int sK) {
  int n = blockIdx.y;
  int k = blockIdx.x * 1024 + threadIdx.x * 4;
  size_t idx = (size_t)n * K + k;
  float sc = s[(n >> 7) * sK + (k >> 7)];
  float4 v = *(const float4*)(wq + idx);
  ushort4 o;
  o.x = f2bf(v.x * sc); o.y = f2bf(v.y * sc);
  o.z = f2bf(v.z * sc); o.w = f2bf(v.w * sc);
  *(ushort4*)(out + idx) = o;
}

// ---------- LDS swizzle ----------
// Tile stored as 128 rows x 8 kblks (kblk = 16B = 8 bf16). Storage index:
//   unit(row, kblk) = row*8 + (kblk ^ (row & 7))
// Fragment reads then touch all 32 banks across every 8 consecutive lanes
// (conflict-free) instead of aliasing at 128B row stride. Staging permutes
// which global kblk each lane loads (lane order within a 128B row segment
// is a permutation -> coalescing preserved; global_load_lds dest stays
// base + lane*16).

// ---------- merged dual GEMM + silu: C = silu(A*B1^T) .* (A*B3^T) ----------
// 512 threads = 8 waves; wave-tile 64(M)x32(N) for both g and u.
// BK=64: 32 K-iterations (vs 64) -> half the barrier drains; 32 MFMA +
// 16 swizzled ds_read_b128 per wave per iteration.
__global__ __launch_bounds__(512, 4) void dual_gemm_silu(
    const unsigned short* __restrict__ A,   // [M,K] bf16 (x)
    const unsigned short* __restrict__ B1,  // [N,K] bf16 (w1)
    const unsigned short* __restrict__ B3,  // [N,K] bf16 (w3)
    unsigned short* __restrict__ C,         // [M,N] bf16 fused
    int M, int N, int K) {
  __shared__ unsigned short As[128 * 64];   // 16 KB
  __shared__ unsigned short B1s[128 * 64];  // 16 KB
  __shared__ unsigned short B3s[128 * 64];  // 16 KB

  const int tid = threadIdx.x;
  const int lane = tid & 63;
  const int wave = tid >> 6;      // 0..7
  const int wm = wave >> 2;       // 0..1  (M 64-half)
  const int wn = wave & 3;        // 0..3  (N 32-quarter)
  const int m0 = blockIdx.y * 128, n0 = blockIdx.x * 128;

  // staging: tile has 1024 16B-units; thread t fills units t and t+512.
  const int s0 = tid, s1 = tid + 512;
  const int r0 = s0 >> 3, c0 = ((s0 & 7) ^ (r0 & 7)) * 8;
  const int r1 = s1 >> 3, c1 = ((s1 & 7) ^ (r1 & 7)) * 8;

  const int q = lane >> 4;        // 0..3
  const int r16 = lane & 15;
  const int rx = r16 & 7;         // row&7 for all fragment rows (rows are
                                  // base(mult of 8) + r16)

  floatx4 acc_g[4][2], acc_u[4][2];
#pragma unroll
  for (int i = 0; i < 4; i++)
#pragma unroll
    for (int j = 0; j < 2; j++) {
      acc_g[i][j] = (floatx4){0.f, 0.f, 0.f, 0.f};
      acc_u[i][j] = (floatx4){0.f, 0.f, 0.f, 0.f};
    }

  const unsigned short* ag0 = A + (size_t)(m0 + r0) * K + c0;
  const unsigned short* ag1 = A + (size_t)(m0 + r1) * K + c1;
  const unsigned short* b1g0 = B1 + (size_t)(n0 + r0) * K + c0;
  const unsigned short* b1g1 = B1 + (size_t)(n0 + r1) * K + c1;
  const unsigned short* b3g0 = B3 + (size_t)(n0 + r0) * K + c0;
  const unsigned short* b3g1 = B3 + (size_t)(n0 + r1) * K + c1;

  for (int k0 = 0; k0 < K; k0 += 64) {
    load16_to_lds(ag0 + k0, &As[s0 * 8]);
    load16_to_lds(ag1 + k0, &As[s1 * 8]);
    load16_to_lds(b1g0 + k0, &B1s[s0 * 8]);
    load16_to_lds(b1g1 + k0, &B1s[s1 * 8]);
    load16_to_lds(b3g0 + k0, &B3s[s0 * 8]);
    load16_to_lds(b3g1 + k0, &B3s[s1 * 8]);
    __syncthreads();

#pragma unroll
    for (int kh = 0; kh < 2; kh++) {
      const int kq = kh * 4 + q;          // kblk 0..7
      short8 a[4], b1v[2], b3v[2];
#pragma unroll
      for (int t = 0; t < 4; t++) {
        int row = wm * 64 + t * 16 + r16;
        a[t] = *(const short8*)&As[(row * 8 + (kq ^ rx)) * 8];
      }
#pragma unroll
      for (int j = 0; j < 2; j++) {
        int row = wn * 32 + j * 16 + r16;
        int u = (row * 8 + (kq ^ rx)) * 8;
        b1v[j] = *(const short8*)&B1s[u];
        b3v[j] = *(const short8*)&B3s[u];
      }
#pragma unroll
      for (int i = 0; i < 4; i++)
#pragma unroll
        for (int j = 0; j < 2; j++) {
          acc_g[i][j] = __builtin_amdgcn_mfma_f32_16x16x32_bf16(
              a[i], b1v[j], acc_g[i][j], 0, 0, 0);
          acc_u[i][j] = __builtin_amdgcn_mfma_f32_16x16x32_bf16(
              a[i], b3v[j], acc_u[i][j], 0, 0, 0);
        }
    }
    __syncthreads();
  }

  // epilogue: D col = lane&15, row = quad*4 + reg (m89/m91-verified)
#pragma unroll
  for (int i = 0; i < 4; i++) {
    int row0 = m0 + wm * 64 + i * 16 + q * 4;
#pragma unroll
    for (int j = 0; j < 2; j++) {
      int col = n0 + wn * 32 + j * 16 + r16;
#pragma unroll
      for (int rr = 0; rr < 4; rr++) {
        float gv = acc_g[i][j][rr];
        float uv = acc_u[i][j][rr];
        float sv = gv / (1.f + __expf(-gv)) * uv;
        C[(size_t)(row0 + rr) * N + col] = f2bf(sv);
      }
    }
  }
}

// ---------- GEMM3: C[M,N] = A[M,K] * B[N,K]^T, bf16 in, fp32 out ----------
// Same 8-wave / BK=64 / swizzled structure, single B.
__global__ __launch_bounds__(512, 4) void gemm_nt_f32_8w(
    const unsigned short* __restrict__ A,  // [M,K] bf16
    const unsigned short* __restrict__ B,  // [N,K] bf16
    float* __restrict__ C,                 // [M,N] fp32
    int M, int N, int K) {
  __shared__ unsigned short As[128 * 64];
  __shared__ unsigned short Bs[128 * 64];

  const int tid = threadIdx.x;
  const int lane = tid & 63;
  const int wave = tid >> 6;
  const int wm = wave >> 2;       // 0..1
  const int wn = wave & 3;        // 0..3
  const int m0 = blockIdx.y * 128, n0 = blockIdx.x * 128;

  const int s0 = tid, s1 = tid + 512;
  const int r0 = s0 >> 3, c0 = ((s0 & 7) ^ (r0 & 7)) * 8;
  const int r1 = s1 >> 3, c1 = ((s1 & 7) ^ (r1 & 7)) * 8;

  const int q = lane >> 4;
  const int r16 = lane & 15;
  const int rx = r16 & 7;

  floatx4 acc[4][2];
#pragma unroll
  for (int i = 0; i < 4; i++)
#pragma unroll
    for (int j = 0; j < 2; j++) acc[i][j] = (floatx4){0.f, 0.f, 0.f, 0.f};

  const unsigned short* ag0 = A + (size_t)(m0 + r0) * K + c0;
  const unsigned short* ag1 = A + (size_t)(m0 + r1) * K + c1;
  const unsigned short* bg0 = B + (size_t)(n0 + r0) * K + c0;
  const unsigned short* bg1 = B + (size_t)(n0 + r1) * K + c1;

  for (int k0 = 0; k0 < K; k0 += 64) {
    load16_to_lds(ag0 + k0, &As[s0 * 8]);
    load16_to_lds(ag1 + k0, &As[s1 * 8]);
    load16_to_lds(bg0 + k0, &Bs[s0 * 8]);
    load16_to_lds(bg1 + k0, &Bs[s1 * 8]);
    __syncthreads();

#pragma unroll
    for (int kh = 0; kh < 2; kh++) {
      const int kq = kh * 4 + q;
      short8 a[4], b[2];
#pragma unroll
      for (int t = 0; t < 4; t++) {
        int row = wm * 64 + t * 16 + r16;
        a[t] = *(const short8*)&As[(row * 8 + (kq ^ rx)) * 8];
      }
#pragma unroll
      for (int j = 0; j < 2; j++) {
        int row = wn * 32 + j * 16 + r16;
        b[j] = *(const short8*)&Bs[(row * 8 + (kq ^ rx)) * 8];
      }
#pragma unroll
      for (int i = 0; i < 4; i++)
#pragma unroll
        for (int j = 0; j < 2; j++)
          acc[i][j] = __builtin_amdgcn_mfma_f32_16x16x32_bf16(
              a[i], b[j], acc[i][j], 0, 0, 0);
    }
    __syncthreads();
  }

#pragma unroll
  for (int i = 0; i < 4; i++) {
    int row0 = m0 + wm * 64 + i * 16 + q * 4;
#pragma unroll
    for (int j = 0; j < 2; j++) {
      int col = n0 + wn * 32 + j * 16 + r16;
#pragma unroll
      for (int rr = 0; rr < 4; rr++)
        C[(size_t)(row0 + rr) * N + col] = acc[i][j][rr];
    }
  }
}

// ---------- launch ----------
extern "C" void kernel_launch(void* const* d_in, const int* in_sizes, int n_in,
                              void* d_out, int out_size, void* d_ws, size_t ws_size,
                              hipStream_t stream) {
  const float* x = (const float*)d_in[0];
  const float* w1q = (const float*)d_in[1];
  const float* w1s = (const float*)d_in[2];
  const float* w3q = (const float*)d_in[3];
  const float* w3s = (const float*)d_in[4];
  const float* w2q = (const float*)d_in[5];
  const float* w2s = (const float*)d_in[6];

  const int T = 4096, H = 2048, F = 7168;

  char* ws = (char*)d_ws;
  unsigned short* xb  = (unsigned short*)ws;  ws += (size_t)T * H * 2;   // 16.8 MB
  unsigned short* w1b = (unsigned short*)ws;  ws += (size_t)F * H * 2;   // 29.4 MB
  unsigned short* w3b = (unsigned short*)ws;  ws += (size_t)F * H * 2;   // 29.4 MB
  unsigned short* w2b = (unsigned short*)ws;  ws += (size_t)H * F * 2;   // 29.4 MB
  unsigned short* g   = (unsigned short*)ws;  ws += (size_t)T * F * 2;   // 58.7 MB

  long xn4 = (long)T * H / 4;

  f32_to_bf16_kernel<<<(xn4 + 255) / 256, 256, 0, stream>>>(x, xb, xn4);
  dequant2_kernel<<<dim3(H / 1024, F), 256, 0, stream>>>(
      w1q, w1s, w3q, w3s, w1b, w3b, H, H / 128);
  dequant1_kernel<<<dim3(F / 1024, H), 256, 0, stream>>>(
      w2q, w2s, w2b, F, F / 128);

  // g = silu(x @ w1^T) * (x @ w3^T)
  dual_gemm_silu<<<dim3(F / 128, T / 128), 512, 0, stream>>>(xb, w1b, w3b, g, T, F, H);

  // out = g @ w2^T  (fp32 out)
  gemm_nt_f32_8w<<<dim3(H / 128, T / 128), 512, 0, stream>>>(g, w2b, (float*)d_out, T, H, F);
}

// Round 7
// 562.003 us; speedup vs baseline: 1.1537x; 1.0209x over previous
//
#include <hip/hip_runtime.h>
#include <stdint.h>

// ---------- helpers ----------
typedef __attribute__((ext_vector_type(8))) short short8;   // 8 x bf16 (4 VGPRs)
typedef __attribute__((ext_vector_type(4))) float floatx4;  // MFMA accum

__device__ __forceinline__ unsigned short f2bf(float f) {
  union { float f; unsigned int u; } c; c.f = f;
  unsigned int u = c.u;
  unsigned int r = (u + 0x7fffu + ((u >> 16) & 1u)) >> 16;  // RNE
  return (unsigned short)r;
}
__device__ __forceinline__ float bf2f(unsigned short h) {
  union { unsigned int u; float f; } c; c.u = ((unsigned int)h) << 16;
  return c.f;
}

// async global->LDS, 16B per lane. LDS dest is wave-uniform base + lane*16.
__device__ __forceinline__ void load16_to_lds(const void* g, void* l) {
  __builtin_amdgcn_global_load_lds(
      (const __attribute__((address_space(1))) unsigned int*)g,
      (__attribute__((address_space(3))) unsigned int*)l, 16, 0, 0);
}

// ---------- elementwise kernels ----------
__global__ void f32_to_bf16_kernel(const float* __restrict__ in,
                                   unsigned short* __restrict__ out, long n4) {
  long i = blockIdx.x * (long)blockDim.x + threadIdx.x;
  if (i >= n4) return;
  float4 v = ((const float4*)in)[i];
  ushort4 o;
  o.x = f2bf(v.x); o.y = f2bf(v.y); o.z = f2bf(v.z); o.w = f2bf(v.w);
  ((ushort4*)out)[i] = o;
}

__global__ void dequant2_kernel(const float* __restrict__ w1q,
                                const float* __restrict__ s1,
                                const float* __restrict__ w3q,
                                const float* __restrict__ s3,
                                unsigned short* __restrict__ o1,
                                unsigned short* __restrict__ o3,
                                int K, int sK) {
  int n = blockIdx.y;
  int k = blockIdx.x * 1024 + threadIdx.x * 4;
  size_t idx = (size_t)n * K + k;
  int sidx = (n >> 7) * sK + (k >> 7);
  float sc1 = s1[sidx], sc3 = s3[sidx];
  float4 v1 = *(const float4*)(w1q + idx);
  float4 v3 = *(const float4*)(w3q + idx);
  ushort4 a, b;
  a.x = f2bf(v1.x * sc1); a.y = f2bf(v1.y * sc1);
  a.z = f2bf(v1.z * sc1); a.w = f2bf(v1.w * sc1);
  b.x = f2bf(v3.x * sc3); b.y = f2bf(v3.y * sc3);
  b.z = f2bf(v3.z * sc3); b.w = f2bf(v3.w * sc3);
  *(ushort4*)(o1 + idx) = a;
  *(ushort4*)(o3 + idx) = b;
}

__global__ void dequant1_kernel(const float* __restrict__ wq,
                                const float* __restrict__ s,
                                unsigned short* __restrict__ out,
                                int K, int sK) {
  int n = blockIdx.y;
  int k = blockIdx.x * 1024 + threadIdx.x * 4;
  size_t idx = (size_t)n * K + k;
  float sc = s[(n >> 7) * sK + (k >> 7)];
  float4 v = *(const float4*)(wq + idx);
  ushort4 o;
  o.x = f2bf(v.x * sc); o.y = f2bf(v.y * sc);
  o.z = f2bf(v.z * sc); o.w = f2bf(v.w * sc);
  *(ushort4*)(out + idx) = o;
}

// ---------- LDS swizzle (R6-verified: conflicts -> 0) ----------
// Tile = 128 rows x 8 kblks (kblk = 16B). unit(row,kblk) = row*8 + (kblk ^ (row&7)).

// ---------- merged dual GEMM + silu: C = silu(A*B1^T) .* (A*B3^T) ----------
// R7: wave-tile 64x64 (was 64x32) -> 12 ds_read_b128 feed 32 MFMAs
// (0.375 reads/MFMA vs 0.5) because R6 analysis shows the LDS read pipe is
// the binding resource (MfmaUtil capped at 44%). 256 threads = 4 waves
// (2x2), block tile 128x128, BK=64. acc 128 + frags 48 VGPRs -> 2 waves/EU,
// 2 blocks/CU (LDS 48 KB/block). launch_bounds(256,2) caps at 256 regs.
__global__ __launch_bounds__(256, 2) void dual_gemm_silu(
    const unsigned short* __restrict__ A,   // [M,K] bf16 (x)
    const unsigned short* __restrict__ B1,  // [N,K] bf16 (w1)
    const unsigned short* __restrict__ B3,  // [N,K] bf16 (w3)
    unsigned short* __restrict__ C,         // [M,N] bf16 fused
    int M, int N, int K) {
  __shared__ unsigned short As[128 * 64];   // 16 KB
  __shared__ unsigned short B1s[128 * 64];  // 16 KB
  __shared__ unsigned short B3s[128 * 64];  // 16 KB

  const int tid = threadIdx.x;
  const int lane = tid & 63;
  const int wave = tid >> 6;      // 0..3
  const int wm = wave >> 1;       // 0..1  (M 64-half)
  const int wn = wave & 1;        // 0..1  (N 64-half)
  const int m0 = blockIdx.y * 128, n0 = blockIdx.x * 128;

  // staging: 1024 16B-units per tile; thread t fills units t+256p, p=0..3,
  // same (row,col) map for all three tiles -> 4 shared offsets.
  int soff[4];   // global element offset for unit p (row*K + swizzled col)
  int sdst[4];   // LDS ushort index
#pragma unroll
  for (int p = 0; p < 4; p++) {
    int u = tid + 256 * p;
    int r = u >> 3;
    int c = ((u & 7) ^ (r & 7)) * 8;
    soff[p] = r * K + c;
    sdst[p] = u * 8;
  }

  const int q = lane >> 4;        // 0..3
  const int r16 = lane & 15;
  const int rx = r16 & 7;         // (row & 7) for all fragment rows

  floatx4 acc_g[4][4], acc_u[4][4];
#pragma unroll
  for (int i = 0; i < 4; i++)
#pragma unroll
    for (int j = 0; j < 4; j++) {
      acc_g[i][j] = (floatx4){0.f, 0.f, 0.f, 0.f};
      acc_u[i][j] = (floatx4){0.f, 0.f, 0.f, 0.f};
    }

  const unsigned short* Abase = A + (size_t)m0 * K;
  const unsigned short* B1base = B1 + (size_t)n0 * K;
  const unsigned short* B3base = B3 + (size_t)n0 * K;

  for (int k0 = 0; k0 < K; k0 += 64) {
#pragma unroll
    for (int p = 0; p < 4; p++) {
      load16_to_lds(Abase + soff[p] + k0, &As[sdst[p]]);
      load16_to_lds(B1base + soff[p] + k0, &B1s[sdst[p]]);
      load16_to_lds(B3base + soff[p] + k0, &B3s[sdst[p]]);
    }
    __syncthreads();

#pragma unroll
    for (int kh = 0; kh < 2; kh++) {
      const int kq = kh * 4 + q;          // kblk 0..7
      short8 a[4], b1v[4], b3v[4];
#pragma unroll
      for (int t = 0; t < 4; t++) {
        int row = wm * 64 + t * 16 + r16;
        a[t] = *(const short8*)&As[(row * 8 + (kq ^ rx)) * 8];
      }
#pragma unroll
      for (int j = 0; j < 4; j++) {
        int row = wn * 64 + j * 16 + r16;
        int u = (row * 8 + (kq ^ rx)) * 8;
        b1v[j] = *(const short8*)&B1s[u];
        b3v[j] = *(const short8*)&B3s[u];
      }
#pragma unroll
      for (int i = 0; i < 4; i++)
#pragma unroll
        for (int j = 0; j < 4; j++) {
          acc_g[i][j] = __builtin_amdgcn_mfma_f32_16x16x32_bf16(
              a[i], b1v[j], acc_g[i][j], 0, 0, 0);
          acc_u[i][j] = __builtin_amdgcn_mfma_f32_16x16x32_bf16(
              a[i], b3v[j], acc_u[i][j], 0, 0, 0);
        }
    }
    __syncthreads();
  }

  // epilogue: D col = lane&15, row = quad*4 + reg (m89/m91-verified)
#pragma unroll
  for (int i = 0; i < 4; i++) {
    int row0 = m0 + wm * 64 + i * 16 + q * 4;
#pragma unroll
    for (int j = 0; j < 4; j++) {
      int col = n0 + wn * 64 + j * 16 + r16;
#pragma unroll
      for (int rr = 0; rr < 4; rr++) {
        float gv = acc_g[i][j][rr];
        float uv = acc_u[i][j][rr];
        float sv = gv / (1.f + __expf(-gv)) * uv;
        C[(size_t)(row0 + rr) * N + col] = f2bf(sv);
      }
    }
  }
}

// ---------- GEMM3: C[M,N] = A[M,K] * B[N,K]^T, bf16 in, fp32 out ----------
// Same 64x64 wave-tile structure, single B: 8 reads / 32 MFMAs per K32.
// acc only 64 regs -> comfortably 2 blocks/CU.
__global__ __launch_bounds__(256, 2) void gemm_nt_f32_4w(
    const unsigned short* __restrict__ A,  // [M,K] bf16
    const unsigned short* __restrict__ B,  // [N,K] bf16
    float* __restrict__ C,                 // [M,N] fp32
    int M, int N, int K) {
  __shared__ unsigned short As[128 * 64];
  __shared__ unsigned short Bs[128 * 64];

  const int tid = threadIdx.x;
  const int lane = tid & 63;
  const int wave = tid >> 6;
  const int wm = wave >> 1;       // 0..1
  const int wn = wave & 1;        // 0..1
  const int m0 = blockIdx.y * 128, n0 = blockIdx.x * 128;

  int soff[4], sdst[4];
#pragma unroll
  for (int p = 0; p < 4; p++) {
    int u = tid + 256 * p;
    int r = u >> 3;
    int c = ((u & 7) ^ (r & 7)) * 8;
    soff[p] = r * K + c;
    sdst[p] = u * 8;
  }

  const int q = lane >> 4;
  const int r16 = lane & 15;
  const int rx = r16 & 7;

  floatx4 acc[4][4];
#pragma unroll
  for (int i = 0; i < 4; i++)
#pragma unroll
    for (int j = 0; j < 4; j++) acc[i][j] = (floatx4){0.f, 0.f, 0.f, 0.f};

  const unsigned short* Abase = A + (size_t)m0 * K;
  const unsigned short* Bbase = B + (size_t)n0 * K;

  for (int k0 = 0; k0 < K; k0 += 64) {
#pragma unroll
    for (int p = 0; p < 4; p++) {
      load16_to_lds(Abase + soff[p] + k0, &As[sdst[p]]);
      load16_to_lds(Bbase + soff[p] + k0, &Bs[sdst[p]]);
    }
    __syncthreads();

#pragma unroll
    for (int kh = 0; kh < 2; kh++) {
      const int kq = kh * 4 + q;
      short8 a[4], b[4];
#pragma unroll
      for (int t = 0; t < 4; t++) {
        int row = wm * 64 + t * 16 + r16;
        a[t] = *(const short8*)&As[(row * 8 + (kq ^ rx)) * 8];
      }
#pragma unroll
      for (int j = 0; j < 4; j++) {
        int row = wn * 64 + j * 16 + r16;
        b[j] = *(const short8*)&Bs[(row * 8 + (kq ^ rx)) * 8];
      }
#pragma unroll
      for (int i = 0; i < 4; i++)
#pragma unroll
        for (int j = 0; j < 4; j++)
          acc[i][j] = __builtin_amdgcn_mfma_f32_16x16x32_bf16(
              a[i], b[j], acc[i][j], 0, 0, 0);
    }
    __syncthreads();
  }

#pragma unroll
  for (int i = 0; i < 4; i++) {
    int row0 = m0 + wm * 64 + i * 16 + q * 4;
#pragma unroll
    for (int j = 0; j < 4; j++) {
      int col = n0 + wn * 64 + j * 16 + r16;
#pragma unroll
      for (int rr = 0; rr < 4; rr++)
        C[(size_t)(row0 + rr) * N + col] = acc[i][j][rr];
    }
  }
}

// ---------- launch ----------
extern "C" void kernel_launch(void* const* d_in, const int* in_sizes, int n_in,
                              void* d_out, int out_size, void* d_ws, size_t ws_size,
                              hipStream_t stream) {
  const float* x = (const float*)d_in[0];
  const float* w1q = (const float*)d_in[1];
  const float* w1s = (const float*)d_in[2];
  const float* w3q = (const float*)d_in[3];
  const float* w3s = (const float*)d_in[4];
  const float* w2q = (const float*)d_in[5];
  const float* w2s = (const float*)d_in[6];

  const int T = 4096, H = 2048, F = 7168;

  char* ws = (char*)d_ws;
  unsigned short* xb  = (unsigned short*)ws;  ws += (size_t)T * H * 2;   // 16.8 MB
  unsigned short* w1b = (unsigned short*)ws;  ws += (size_t)F * H * 2;   // 29.4 MB
  unsigned short* w3b = (unsigned short*)ws;  ws += (size_t)F * H * 2;   // 29.4 MB
  unsigned short* w2b = (unsigned short*)ws;  ws += (size_t)H * F * 2;   // 29.4 MB
  unsigned short* g   = (unsigned short*)ws;  ws += (size_t)T * F * 2;   // 58.7 MB

  long xn4 = (long)T * H / 4;

  f32_to_bf16_kernel<<<(xn4 + 255) / 256, 256, 0, stream>>>(x, xb, xn4);
  dequant2_kernel<<<dim3(H / 1024, F), 256, 0, stream>>>(
      w1q, w1s, w3q, w3s, w1b, w3b, H, H / 128);
  dequant1_kernel<<<dim3(F / 1024, H), 256, 0, stream>>>(
      w2q, w2s, w2b, F, F / 128);

  // g = silu(x @ w1^T) * (x @ w3^T)
  dual_gemm_silu<<<dim3(F / 128, T / 128), 256, 0, stream>>>(xb, w1b, w3b, g, T, F, H);

  // out = g @ w2^T  (fp32 out)
  gemm_nt_f32_4w<<<dim3(H / 128, T / 128), 256, 0, stream>>>(g, w2b, (float*)d_out, T, H, F);
}